// Round 5
// baseline (3732.133 us; speedup 1.0000x reference)
//
#include <hip/hip_runtime.h>
#include <hip/hip_bf16.h>
#include <math.h>

typedef unsigned short u16;
typedef __attribute__((ext_vector_type(8))) __bf16 bf16x8;
typedef __attribute__((ext_vector_type(4))) float f32x4;

#define LSTM_L 200
#define LSTM_B 2048
#define LSTM_HIN 64
#define LSTM_H 256
#define NCLUST 64
#define HALF_BETA 0.05f
#define LDS_BYTES 131072

__device__ __forceinline__ void gload_lds16(const void* g, void* l) {
    __builtin_amdgcn_global_load_lds(
        (__attribute__((address_space(1))) const void*)g,
        (__attribute__((address_space(3))) void*)l, 16, 0, 0);
}

__device__ __forceinline__ float fast_sigmoid(float x) {
    return __builtin_amdgcn_rcpf(1.f + __expf(-x));
}
__device__ __forceinline__ float fast_tanh(float x) {
    return 2.f * __builtin_amdgcn_rcpf(1.f + __expf(-2.f * x)) - 1.f;
}

// ---------------------------------------------------------------------------
// Weight pack into per-(nb,wn) fragment order (identical to round 4):
// i = ((((nb*4+wn)*NCH + ch)*2 + nf)*64 + lane)*8 + e
// j = (2*nf + (l15&1))*256 + nb*32 + wn*8 + (l15>>1); k = ch*32 + (lane>>4)*8 + e
// ---------------------------------------------------------------------------
template<int KIN>
__global__ __launch_bounds__(256) void pack_frag(
    const float* __restrict__ Wih, const float* __restrict__ Whh,
    u16* __restrict__ Wp)
{
    constexpr int NCH = (KIN + LSTM_H) / 32;
    const int total = 1024 * (KIN + LSTM_H);
    for (int i = blockIdx.x * 256 + threadIdx.x; i < total; i += gridDim.x * 256) {
        const int e = i & 7;
        int t = i >> 3;
        const int lane = t & 63; t >>= 6;
        const int nf = t & 1;    t >>= 1;
        const int ch = t % NCH;  t /= NCH;
        const int wn = t & 3;
        const int nb = t >> 2;
        const int l15 = lane & 15;
        const int j = (2 * nf + (l15 & 1)) * 256 + nb * 32 + wn * 8 + (l15 >> 1);
        const int k = ch * 32 + ((lane >> 4) << 3) + e;
        const float v = (k < KIN) ? Wih[(size_t)j * KIN + k]
                                  : Whh[(size_t)j * LSTM_H + (k - KIN)];
        Wp[i] = __builtin_bit_cast(u16, (__bf16)v);
    }
}

// ---------------------------------------------------------------------------
// Persistent LSTM, flag-synced. 256 blocks x 512 thr. bi&15 = mb (XCD-local
// groups under round-robin dispatch, heuristic only); (bi>>4)&1 = layer;
// bi>>5 = nb. Per slot s: L0 computes step s, L1 computes step s-1.
// Counters cnt0/cnt1[mb]: +1 per writer per slot (8 writers/group/slot).
// Waits at slot s: cnt0 >= 8s (h0^{s-1} ready + peer RAW/WAR) and
// cnt1 >= 8(s-1) (h1^{s-2} ready + WAR on ping-pong buffers).
// c-state in registers for the whole sequence. Weights in VGPRs.
// ---------------------------------------------------------------------------
__device__ __forceinline__ void lstm_pointwise_store(
    f32x4 acc[4][2], float cp[4][4], float b0a, float b1a, int gpar,
    int b0, int rowA, int q, int hcol, u16* hout, float* latout)
{
#pragma unroll
    for (int mf = 0; mf < 4; ++mf) {
#pragma unroll
        for (int r = 0; r < 4; ++r) {
            const float a0 = acc[mf][0][r] + b0a;
            const float a1 = acc[mf][1][r] + b1a;
            const float p0 = __shfl_xor(a0, 1);
            const float p1 = __shfl_xor(a1, 1);
            const float gi = gpar ? p0 : a0;
            const float gf = gpar ? a0 : p0;
            const float gg = gpar ? p1 : a1;
            const float go = gpar ? a1 : p1;
            const float cn = fast_sigmoid(gf) * cp[mf][r]
                           + fast_sigmoid(gi) * fast_tanh(gg);
            cp[mf][r] = cn;
            const float hv = fast_sigmoid(go) * fast_tanh(cn);
            if (!gpar) {
                const size_t oidx =
                    (size_t)(b0 + rowA + mf * 16 + q * 4 + r) * 256 + hcol;
                if (latout) latout[oidx] = hv;
                else hout[oidx] = __builtin_bit_cast(u16, (__bf16)hv);
            }
        }
    }
}

__device__ void l0_persist(
    const float* __restrict__ X, const u16* __restrict__ Wp0,
    const float* __restrict__ bih0, const float* __restrict__ bhh0,
    u16* h0b0, u16* h0b1, int* c0p, int* c1p,
    int mb, int nb, char* smem, int tid)
{
    constexpr int NCH = 10;
    const int lane = tid & 63, w = tid >> 6, wm = w >> 2, wn = w & 3;
    const int l15 = lane & 15, q = lane >> 4;
    const int b0 = mb * 128;
    u16* hb[2] = {h0b0, h0b1};

    bf16x8 Breg[NCH][2];
    {
        const u16* wp = Wp0 + (size_t)((nb * 4 + wn) * NCH) * 1024 + lane * 8;
#pragma unroll
        for (int ch = 0; ch < NCH; ++ch)
#pragma unroll
            for (int nf = 0; nf < 2; ++nf)
                Breg[ch][nf] = *(const bf16x8*)(wp + (ch * 2 + nf) * 512);
    }
    const int hcol = nb * 32 + wn * 8 + (l15 >> 1);
    const int gpar = l15 & 1;
    const float b0a = bih0[gpar * 256 + hcol] + bhh0[gpar * 256 + hcol];
    const float b1a = bih0[(2 + gpar) * 256 + hcol] + bhh0[(2 + gpar) * 256 + hcol];
    const int rowA = wm * 64;
    const int qoff = q * 16, swzl = (l15 & 7) << 4;

    float cp[4][4];
#pragma unroll
    for (int mf = 0; mf < 4; ++mf)
#pragma unroll
        for (int r = 0; r < 4; ++r) cp[mf][r] = 0.f;

    for (int s = 0; s < LSTM_L; ++s) {
        // prefetch X (regs) before the wait — hides HBM latency
        float4 xv[2][2];
#pragma unroll
        for (int p = 0; p < 2; ++p) {
            const int slot = p * 512 + tid;
            const int row = slot >> 3;
            const int so = (slot & 7) * 16;
            const int koff = so ^ ((row & 7) << 4);
            const float* sp = X + (size_t)s * LSTM_B * LSTM_HIN
                              + (size_t)(b0 + row) * 64 + (koff >> 1);
            xv[p][0] = *(const float4*)sp;
            xv[p][1] = *(const float4*)(sp + 4);
        }
        if (tid == 0) {
            if (s >= 1)
                while (__hip_atomic_load(c0p, __ATOMIC_RELAXED,
                                         __HIP_MEMORY_SCOPE_AGENT) < 8 * s)
                    __builtin_amdgcn_s_sleep(1);
            if (s >= 2)
                while (__hip_atomic_load(c1p, __ATOMIC_RELAXED,
                                         __HIP_MEMORY_SCOPE_AGENT) < 8 * (s - 1))
                    __builtin_amdgcn_s_sleep(1);
            if (s >= 1) __builtin_amdgcn_fence(__ATOMIC_ACQUIRE, "agent");
        }
        __syncthreads();
        // stage h0^{s-1} -> LDS [128][512B] swizzled
        const u16* hself = hb[(s + 1) & 1];
#pragma unroll
        for (int i = 0; i < 8; ++i) {
            const int slot = i * 512 + tid;
            const int row = slot >> 5;
            const int so = (slot & 31) * 16;
            const int koff = so ^ ((row & 7) << 4);
            gload_lds16((const char*)hself + (size_t)(b0 + row) * 512 + koff,
                        smem + slot * 16);
        }
        // X region [128][128B] at 65536 from prefetched regs
#pragma unroll
        for (int p = 0; p < 2; ++p) {
            const int slot = p * 512 + tid;
            bf16x8 pk;
            pk[0] = (__bf16)xv[p][0].x; pk[1] = (__bf16)xv[p][0].y;
            pk[2] = (__bf16)xv[p][0].z; pk[3] = (__bf16)xv[p][0].w;
            pk[4] = (__bf16)xv[p][1].x; pk[5] = (__bf16)xv[p][1].y;
            pk[6] = (__bf16)xv[p][1].z; pk[7] = (__bf16)xv[p][1].w;
            *(bf16x8*)(smem + 65536 + slot * 16) = pk;
        }
        __syncthreads();

        f32x4 acc[4][2];
#pragma unroll
        for (int mf = 0; mf < 4; ++mf)
#pragma unroll
            for (int nf = 0; nf < 2; ++nf) acc[mf][nf] = f32x4{0.f,0.f,0.f,0.f};
#pragma unroll
        for (int ch = 0; ch < NCH; ++ch) {
            bf16x8 af[4];
#pragma unroll
            for (int mf = 0; mf < 4; ++mf) {
                const int row = rowA + mf * 16 + l15;
                const char* ap = (ch < 2)
                    ? smem + 65536 + row * 128 + ((ch * 64 + qoff) ^ swzl)
                    : smem + row * 512 + (((ch - 2) * 64 + qoff) ^ swzl);
                af[mf] = *(const bf16x8*)ap;
            }
#pragma unroll
            for (int mf = 0; mf < 4; ++mf)
#pragma unroll
                for (int nf = 0; nf < 2; ++nf)
                    acc[mf][nf] = __builtin_amdgcn_mfma_f32_16x16x32_bf16(
                        af[mf], Breg[ch][nf], acc[mf][nf], 0, 0, 0);
        }
        lstm_pointwise_store(acc, cp, b0a, b1a, gpar, b0, rowA, q, hcol,
                             hb[s & 1], nullptr);
        __syncthreads();   // drain stores (waitcnt before barrier)
        if (tid == 0) {
            __builtin_amdgcn_fence(__ATOMIC_RELEASE, "agent");
            __hip_atomic_fetch_add(c0p, 1, __ATOMIC_RELAXED,
                                   __HIP_MEMORY_SCOPE_AGENT);
        }
    }
}

__device__ void l1_persist(
    const u16* __restrict__ Wp1,
    const float* __restrict__ bih1, const float* __restrict__ bhh1,
    u16* h0b0, u16* h0b1, u16* h1b0, u16* h1b1,
    float* __restrict__ latent, int* c0p, int* c1p,
    int mb, int nb, char* smem, int tid)
{
    constexpr int NCH = 16;
    const int lane = tid & 63, w = tid >> 6, wm = w >> 2, wn = w & 3;
    const int l15 = lane & 15, q = lane >> 4;
    const int b0 = mb * 128;
    u16* h0b[2] = {h0b0, h0b1};
    u16* h1b[2] = {h1b0, h1b1};

    bf16x8 Breg[NCH][2];
    {
        const u16* wp = Wp1 + (size_t)((nb * 4 + wn) * NCH) * 1024 + lane * 8;
#pragma unroll
        for (int ch = 0; ch < NCH; ++ch)
#pragma unroll
            for (int nf = 0; nf < 2; ++nf)
                Breg[ch][nf] = *(const bf16x8*)(wp + (ch * 2 + nf) * 512);
    }
    const int hcol = nb * 32 + wn * 8 + (l15 >> 1);
    const int gpar = l15 & 1;
    const float b0a = bih1[gpar * 256 + hcol] + bhh1[gpar * 256 + hcol];
    const float b1a = bih1[(2 + gpar) * 256 + hcol] + bhh1[(2 + gpar) * 256 + hcol];
    const int rowA = wm * 64;
    const int qoff = q * 16, swzl = (l15 & 7) << 4;

    float cp[4][4];
#pragma unroll
    for (int mf = 0; mf < 4; ++mf)
#pragma unroll
        for (int r = 0; r < 4; ++r) cp[mf][r] = 0.f;

    for (int s = 1; s <= LSTM_L; ++s) {
        if (tid == 0) {
            while (__hip_atomic_load(c0p, __ATOMIC_RELAXED,
                                     __HIP_MEMORY_SCOPE_AGENT) < 8 * s)
                __builtin_amdgcn_s_sleep(1);
            if (s >= 2)
                while (__hip_atomic_load(c1p, __ATOMIC_RELAXED,
                                         __HIP_MEMORY_SCOPE_AGENT) < 8 * (s - 1))
                    __builtin_amdgcn_s_sleep(1);
            __builtin_amdgcn_fence(__ATOMIC_ACQUIRE, "agent");
        }
        __syncthreads();
        // stage [128][1024B]: bytes 0..511 = h0^{s-1}, 512..1023 = h1^{s-2}
        const u16* hbelow = h0b[(s + 1) & 1];
        const u16* hself  = h1b[s & 1];
#pragma unroll
        for (int i = 0; i < 16; ++i) {
            const int slot = i * 512 + tid;
            const int row = slot >> 6;
            const int so = (slot & 63) * 16;
            const int koff = so ^ ((row & 7) << 4);
            const char* src = (koff < 512)
                ? (const char*)hbelow + (size_t)(b0 + row) * 512 + koff
                : (const char*)hself + (size_t)(b0 + row) * 512 + (koff - 512);
            gload_lds16(src, smem + slot * 16);
        }
        __syncthreads();

        f32x4 acc[4][2];
#pragma unroll
        for (int mf = 0; mf < 4; ++mf)
#pragma unroll
            for (int nf = 0; nf < 2; ++nf) acc[mf][nf] = f32x4{0.f,0.f,0.f,0.f};
#pragma unroll
        for (int ch = 0; ch < NCH; ++ch) {
            bf16x8 af[4];
#pragma unroll
            for (int mf = 0; mf < 4; ++mf) {
                const int row = rowA + mf * 16 + l15;
                const char* ap = smem + row * 1024 + ((ch * 64 + qoff) ^ swzl);
                af[mf] = *(const bf16x8*)ap;
            }
#pragma unroll
            for (int mf = 0; mf < 4; ++mf)
#pragma unroll
                for (int nf = 0; nf < 2; ++nf)
                    acc[mf][nf] = __builtin_amdgcn_mfma_f32_16x16x32_bf16(
                        af[mf], Breg[ch][nf], acc[mf][nf], 0, 0, 0);
        }
        lstm_pointwise_store(acc, cp, b0a, b1a, gpar, b0, rowA, q, hcol,
                             h1b[(s + 1) & 1],
                             (s == LSTM_L) ? latent : nullptr);
        __syncthreads();
        if (tid == 0 && s < LSTM_L) {
            __builtin_amdgcn_fence(__ATOMIC_RELEASE, "agent");
            __hip_atomic_fetch_add(c1p, 1, __ATOMIC_RELAXED,
                                   __HIP_MEMORY_SCOPE_AGENT);
        }
    }
}

__global__ __launch_bounds__(512, 2) void lstm_persist2(
    const float* __restrict__ X,
    const u16* __restrict__ Wp0, const u16* __restrict__ Wp1,
    const float* __restrict__ bih0, const float* __restrict__ bhh0,
    const float* __restrict__ bih1, const float* __restrict__ bhh1,
    u16* h0b0, u16* h0b1, u16* h1b0, u16* h1b1,
    float* __restrict__ latent, int* cnt0, int* cnt1)
{
    extern __shared__ char smem[];
    const int tid = threadIdx.x;
    const int bi = (int)blockIdx.x;
    const int mb = bi & 15;          // group id: same (bi % 8) => same XCD
    const int rest = bi >> 4;
    const int layer = rest & 1;
    const int nb = rest >> 1;
    int* c0p = cnt0 + mb * 16;
    int* c1p = cnt1 + mb * 16;
    if (layer == 0)
        l0_persist(X, Wp0, bih0, bhh0, h0b0, h0b1, c0p, c1p, mb, nb, smem, tid);
    else
        l1_persist(Wp1, bih1, bhh1, h0b0, h0b1, h1b0, h1b1, latent,
                   c0p, c1p, mb, nb, smem, tid);
}

// ---------------------------------------------------------------------------
// K-means tail: assign + atomic accumulation, then finalize, then loss.
// ---------------------------------------------------------------------------
__global__ __launch_bounds__(64) void assign_accum(
    const float* __restrict__ lat, const float* __restrict__ clusters,
    int* __restrict__ ids, float* __restrict__ sums, int* __restrict__ counts)
{
    __shared__ float row[LSTM_H];
    const int b = blockIdx.x;
    const int k = threadIdx.x;
    for (int i = k; i < LSTM_H; i += 64) row[i] = lat[(size_t)b * LSTM_H + i];
    __syncthreads();
    const float* ck = clusters + (size_t)k * LSTM_H;
    float d = 0.f;
#pragma unroll 8
    for (int i = 0; i < LSTM_H; ++i) { const float t = row[i] - ck[i]; d += t * t; }
    int idx = k;
    for (int off = 32; off > 0; off >>= 1) {
        const float od = __shfl_down(d, off, 64);
        const int   oi = __shfl_down(idx, off, 64);
        if (od < d || (od == d && oi < idx)) { d = od; idx = oi; }
    }
    const int best = __shfl(idx, 0, 64);
    if (k == 0) { ids[b] = best; atomicAdd(&counts[best], 1); }
#pragma unroll
    for (int j = 0; j < 4; ++j)
        atomicAdd(&sums[(size_t)best * LSTM_H + k * 4 + j], row[k * 4 + j]);
}

__global__ __launch_bounds__(256) void centroid_final(
    const float* __restrict__ sums, const int* __restrict__ counts,
    const float* __restrict__ clusters, float* __restrict__ upd)
{
    const int k = blockIdx.x;
    const int h = threadIdx.x;
    const int c = counts[k];
    upd[(size_t)k * LSTM_H + h] = (c > 0)
        ? sums[(size_t)k * LSTM_H + h] / (float)c
        : clusters[(size_t)k * LSTM_H + h];
}

__global__ __launch_bounds__(256) void loss_kernel(
    const float* __restrict__ lat, const int* __restrict__ ids,
    const float* __restrict__ upd, float* __restrict__ out_loss)
{
    float p = 0.f;
    const int total = LSTM_B * LSTM_H;
    for (int idx = blockIdx.x * blockDim.x + threadIdx.x; idx < total;
         idx += gridDim.x * blockDim.x) {
        const int b = idx >> 8;
        const float d = lat[idx] - upd[(size_t)ids[b] * LSTM_H + (idx & 255)];
        p += d * d;
    }
    for (int off = 32; off > 0; off >>= 1) p += __shfl_down(p, off, 64);
    __shared__ float wsum[4];
    const int lane = threadIdx.x & 63, wid = threadIdx.x >> 6;
    if (lane == 0) wsum[wid] = p;
    __syncthreads();
    if (threadIdx.x == 0)
        atomicAdd(out_loss, HALF_BETA * (wsum[0] + wsum[1] + wsum[2] + wsum[3]));
}

// ---------------------------------------------------------------------------
extern "C" void kernel_launch(void* const* d_in, const int* in_sizes, int n_in,
                              void* d_out, int out_size, void* d_ws, size_t ws_size,
                              hipStream_t stream)
{
    const float* X     = (const float*)d_in[0];
    const float* Wih0  = (const float*)d_in[1];
    const float* Whh0  = (const float*)d_in[2];
    const float* bih0  = (const float*)d_in[3];
    const float* bhh0  = (const float*)d_in[4];
    const float* Wih1  = (const float*)d_in[5];
    const float* Whh1  = (const float*)d_in[6];
    const float* bih1  = (const float*)d_in[7];
    const float* bhh1  = (const float*)d_in[8];
    const float* clust = (const float*)d_in[9];

    float* out = (float*)d_out;
    char* base = (char*)d_ws;
    const size_t MB = 1u << 20;
    const size_t KB = 1024;

    u16* Wp0    = (u16*)(base + 0 * MB);             // 640 KB
    u16* Wp1    = (u16*)(base + 1 * MB);             // 1 MB
    u16* h0b0   = (u16*)(base + 2 * MB);             // 1 MB each
    u16* h0b1   = (u16*)(base + 3 * MB);
    u16* h1b0   = (u16*)(base + 4 * MB);
    u16* h1b1   = (u16*)(base + 5 * MB);
    float* sums = (float*)(base + 6 * MB);           // 64 KB
    float* upd  = (float*)(base + 6 * MB + 64 * KB); // 64 KB
    int* counts = (int*)(base + 6 * MB + 128 * KB);  // 256 B (1 KB resv)
    int* ids    = (int*)(base + 6 * MB + 132 * KB);  // 8 KB
    int* cnt0   = (int*)(base + 6 * MB + 144 * KB);  // 1 KB
    int* cnt1   = (int*)(base + 6 * MB + 148 * KB);  // 1 KB

    const size_t BH = (size_t)LSTM_B * LSTM_H;

    // zero: "step -1" h buffers, tail scratch (sums/counts/flags), loss slot
    hipMemsetAsync(h0b1, 0, MB, stream);
    hipMemsetAsync(h1b1, 0, MB, stream);
    hipMemsetAsync(base + 6 * MB, 0, 152 * KB, stream);
    hipMemsetAsync(out + BH, 0, sizeof(float), stream);

    pack_frag<LSTM_HIN><<<320, 256, 0, stream>>>(Wih0, Whh0, Wp0);
    pack_frag<LSTM_H>  <<<512, 256, 0, stream>>>(Wih1, Whh1, Wp1);

    hipFuncSetAttribute((const void*)lstm_persist2,
                        hipFuncAttributeMaxDynamicSharedMemorySize, LDS_BYTES);

    float* lat = out;
    void* args[] = {
        (void*)&X, (void*)&Wp0, (void*)&Wp1,
        (void*)&bih0, (void*)&bhh0, (void*)&bih1, (void*)&bhh1,
        (void*)&h0b0, (void*)&h0b1, (void*)&h1b0, (void*)&h1b1,
        (void*)&lat, (void*)&cnt0, (void*)&cnt1
    };
    hipLaunchCooperativeKernel((void*)lstm_persist2, dim3(256), dim3(512),
                               args, LDS_BYTES, stream);

    assign_accum<<<LSTM_B, 64, 0, stream>>>(out, clust, ids, sums, counts);
    centroid_final<<<NCLUST, 256, 0, stream>>>(sums, counts, clust, upd);
    loss_kernel<<<256, 256, 0, stream>>>(out, ids, upd, out + BH);
}